// Round 2
// baseline (415.042 us; speedup 1.0000x reference)
//
#include <hip/hip_runtime.h>
#include <hip/hip_bf16.h>

#define T_ 2048
#define D_ 2048
#define H_ 16
#define HD_ 128

typedef __hip_bfloat16 bf16;
using bf16x8 = __attribute__((ext_vector_type(8))) short;   // 8 bf16 = 4 VGPRs
using f32x4  = __attribute__((ext_vector_type(4))) float;

#define GLL16(g, l) __builtin_amdgcn_global_load_lds( \
    (const __attribute__((address_space(1))) void*)(g), \
    (__attribute__((address_space(3))) void*)(l), 16, 0, 0)

__device__ __forceinline__ f32x4 mfma16(bf16x8 a, bf16x8 b, f32x4 c) {
    return __builtin_amdgcn_mfma_f32_16x16x32_bf16(a, b, c, 0, 0, 0);
}

// ---------- cast fp32 -> bf16: 6 uniform chunks of 4194304 elems ----------
__global__ __launch_bounds__(256) void cast6(
    const float* __restrict__ s0, const float* __restrict__ s1,
    const float* __restrict__ s2, const float* __restrict__ s3,
    const float* __restrict__ s4, const float* __restrict__ s5,
    bf16* __restrict__ dst)
{
    int z = blockIdx.y;
    const float* s = (z == 0) ? s0 : (z == 1) ? s1 : (z == 2) ? s2
                   : (z == 3) ? s3 : (z == 4) ? s4 : s5;
    long i = ((long)blockIdx.x * 256 + threadIdx.x) * 8;
    float4 a = *(const float4*)(s + i);
    float4 b = *(const float4*)(s + i + 4);
    union { bf16 h[8]; int4 v; } u;
    u.h[0] = __float2bfloat16(a.x); u.h[1] = __float2bfloat16(a.y);
    u.h[2] = __float2bfloat16(a.z); u.h[3] = __float2bfloat16(a.w);
    u.h[4] = __float2bfloat16(b.x); u.h[5] = __float2bfloat16(b.y);
    u.h[6] = __float2bfloat16(b.z); u.h[7] = __float2bfloat16(b.w);
    *(int4*)(dst + (long)z * 4194304 + i) = u.v;
}

// ============================================================================
// QKV as ONE fused GEMM: C[4096][6144] = X[4096][2048] @ Wall[6144][2048]^T
// (wq/wk/wv contiguous in workspace). 256x256 tile, BK=64, 8 waves (2Mx4N),
// per-wave output 128x64 (reads/MFMA = 0.375 -> under the LDS-BW roof).
// 8-phase schedule (T3+T4): per K-tile 4 phases, each
//   {ds_read subtile, stage 1 half-tile, barrier, lgkmcnt(0), 16 MFMA, barrier}
// st_16x32 LDS swizzle (T2): byte ^= ((byte>>9)&1)<<5 == elem col ^ ((row>>2)&1)<<4,
// applied as inverse-swizzled GLOBAL source (linear gload_lds dest) + swizzled read.
// Staging schedule (race-checked):
//   tile t phases stage: ph1 t+1.B0, ph2 t+1.B1 (opposite buffer -> always safe),
//   ph3 t+2.A0, ph4 t+2.A1 (same buffer as t, but A-halves' last ds_read is ph2;
//   issue is after the ph2 trailing barrier -> safe).
//   vmcnt(4) once per tile at ph4: everything except the last 2 half-tiles
//   (t+2.A0/A1) has landed -> t+1 fully resident before its compute.
// ============================================================================

#define SA(t, h, b) do { \
    GLL16(Ab0 + (long)(h)*262144 + (t)*64,          &Asm[b][h][tid*8]); \
    GLL16(Ab0 + (long)(h)*262144 + 131072 + (t)*64, &Asm[b][h][4096 + tid*8]); \
} while (0)
#define SB(t, h, b) do { \
    GLL16(Bb0 + (long)(h)*262144 + (t)*64,          &Bsm[b][h][tid*8]); \
    GLL16(Bb0 + (long)(h)*262144 + 131072 + (t)*64, &Bsm[b][h][4096 + tid*8]); \
} while (0)

#define RA(mf, ks) (*(const bf16x8*)&Asm[buf][wr][((mf)*16 + l15)*64 + ((((ks)*32) + g8) ^ swF)])
#define RB(nf, ks) (*(const bf16x8*)&Bsm[buf][wc>>1][((wc&1)*64 + (nf)*16 + l15)*64 + ((((ks)*32) + g8) ^ swF)])

#define PH_SYNC() do { \
    __builtin_amdgcn_s_barrier(); \
    asm volatile("s_waitcnt lgkmcnt(0)" ::: "memory"); \
    __builtin_amdgcn_sched_barrier(0); \
} while (0)

__global__ __launch_bounds__(512) void gemm_qkv256(
    const bf16* __restrict__ xb, const bf16* __restrict__ Wall,
    bf16* __restrict__ QKV)   // 3 x [B,H,T,HD] contiguous
{
    __shared__ bf16 Asm[2][2][8192];   // [buf][half][128*64]
    __shared__ bf16 Bsm[2][2][8192];
    int tid = threadIdx.x, lane = tid & 63, wid = tid >> 6;
    int wr = wid >> 2, wc = wid & 3;
    // XCD-aware bijective swizzle (nwg = 384, 384 % 8 == 0)
    int orig = blockIdx.x;
    int wg = (orig & 7) * 48 + (orig >> 3);
    int bm = wg / 24, bn = wg - bm * 24;          // 16 x 24

    // staging: thread covers row sr (and sr+64) of a [128][64] half-tile
    int sr  = tid >> 3;
    int swS = ((sr >> 2) & 1) << 4;               // st_16x32: flip 16-elem group
    int sc  = ((tid & 7) * 8) ^ swS;              // pre-swizzled source column
    const bf16* Ab0 = xb   + ((long)(bm * 256 + sr)) * 2048 + sc;
    const bf16* Bb0 = Wall + ((long)(bn * 256 + sr)) * 2048 + sc;

    // fragment-read constants
    int l15 = lane & 15, g8 = (lane >> 4) * 8;
    int swF = ((lane >> 2) & 1) << 4;             // (row>>2)&1 depends only on lane&15

    f32x4 acc[8][4];
    #pragma unroll
    for (int i = 0; i < 8; ++i)
        #pragma unroll
        for (int j = 0; j < 4; ++j) acc[i][j] = f32x4{0.f, 0.f, 0.f, 0.f};

    bf16x8 Ar[8][2];   // [mf][ks]
    bf16x8 Br[4][2];   // [nf][ks]

    // prologue: t0 complete + t1 A-halves in flight
    SA(0, 0, 0); SA(0, 1, 0); SB(0, 0, 0); SB(0, 1, 0);
    SA(1, 0, 1); SA(1, 1, 1);
    asm volatile("s_waitcnt vmcnt(4)" ::: "memory");
    __builtin_amdgcn_s_barrier();

    const int NT = D_ / 64;   // 32
    for (int t = 0; t < NT; ++t) {
        int buf = t & 1, nbuf = buf ^ 1;
        // ---- phase 1: read A(mf0-3) + B(nf0-1); stage t+1.B0; MFMA q(0,0) ----
        #pragma unroll
        for (int mf = 0; mf < 4; ++mf) { Ar[mf][0] = RA(mf, 0); Ar[mf][1] = RA(mf, 1); }
        #pragma unroll
        for (int nf = 0; nf < 2; ++nf) { Br[nf][0] = RB(nf, 0); Br[nf][1] = RB(nf, 1); }
        if (t + 1 < NT) SB(t + 1, 0, nbuf);
        PH_SYNC();
        __builtin_amdgcn_s_setprio(1);
        #pragma unroll
        for (int mf = 0; mf < 4; ++mf)
            #pragma unroll
            for (int nf = 0; nf < 2; ++nf) {
                acc[mf][nf] = mfma16(Ar[mf][0], Br[nf][0], acc[mf][nf]);
                acc[mf][nf] = mfma16(Ar[mf][1], Br[nf][1], acc[mf][nf]);
            }
        __builtin_amdgcn_s_setprio(0);
        __builtin_amdgcn_s_barrier();
        // ---- phase 2: read A(mf4-7); stage t+1.B1; MFMA q(1,0) ----
        #pragma unroll
        for (int mf = 4; mf < 8; ++mf) { Ar[mf][0] = RA(mf, 0); Ar[mf][1] = RA(mf, 1); }
        if (t + 1 < NT) SB(t + 1, 1, nbuf);
        PH_SYNC();
        __builtin_amdgcn_s_setprio(1);
        #pragma unroll
        for (int mf = 4; mf < 8; ++mf)
            #pragma unroll
            for (int nf = 0; nf < 2; ++nf) {
                acc[mf][nf] = mfma16(Ar[mf][0], Br[nf][0], acc[mf][nf]);
                acc[mf][nf] = mfma16(Ar[mf][1], Br[nf][1], acc[mf][nf]);
            }
        __builtin_amdgcn_s_setprio(0);
        __builtin_amdgcn_s_barrier();
        // ---- phase 3: read B(nf2-3); stage t+2.A0 (A reads done at ph2); MFMA q(0,1) ----
        #pragma unroll
        for (int nf = 2; nf < 4; ++nf) { Br[nf][0] = RB(nf, 0); Br[nf][1] = RB(nf, 1); }
        if (t + 2 < NT) SA(t + 2, 0, buf);
        PH_SYNC();
        __builtin_amdgcn_s_setprio(1);
        #pragma unroll
        for (int mf = 0; mf < 4; ++mf)
            #pragma unroll
            for (int nf = 2; nf < 4; ++nf) {
                acc[mf][nf] = mfma16(Ar[mf][0], Br[nf][0], acc[mf][nf]);
                acc[mf][nf] = mfma16(Ar[mf][1], Br[nf][1], acc[mf][nf]);
            }
        __builtin_amdgcn_s_setprio(0);
        __builtin_amdgcn_s_barrier();
        // ---- phase 4: stage t+2.A1; vmcnt(4); MFMA q(1,1) ----
        if (t + 2 < NT) {
            SA(t + 2, 1, buf);
            asm volatile("s_waitcnt vmcnt(4)" ::: "memory");
        } else {
            asm volatile("s_waitcnt vmcnt(0)" ::: "memory");
        }
        __builtin_amdgcn_s_barrier();
        __builtin_amdgcn_s_setprio(1);
        #pragma unroll
        for (int mf = 4; mf < 8; ++mf)
            #pragma unroll
            for (int nf = 2; nf < 4; ++nf) {
                acc[mf][nf] = mfma16(Ar[mf][0], Br[nf][0], acc[mf][nf]);
                acc[mf][nf] = mfma16(Ar[mf][1], Br[nf][1], acc[mf][nf]);
            }
        __builtin_amdgcn_s_setprio(0);
        __builtin_amdgcn_s_barrier();
    }

    // epilogue: C[m][n], n in [0,6144) -> z = n>>11, h = (n&2047)>>7, hd = n&127
    int mBase = bm * 256 + wr * 128;
    int nBase = bn * 256 + wc * 64;
    #pragma unroll
    for (int mf = 0; mf < 8; ++mf) {
        #pragma unroll
        for (int nf = 0; nf < 4; ++nf) {
            int n = nBase + nf * 16 + l15;
            int z = n >> 11, n2 = n & 2047;
            int h = n2 >> 7, hd = n2 & 127;
            #pragma unroll
            for (int r = 0; r < 4; ++r) {
                int m = mBase + mf * 16 + (lane >> 4) * 4 + r;
                int b = m >> 11, tt = m & 2047;
                QKV[(long)z * 8388608 + (((long)(b * H_ + h)) * T_ + tt) * HD_ + hd] =
                    __float2bfloat16(acc[mf][nf][r]);
            }
        }
    }
}

// ============================================================================
// gemm_out keeps the round-1 ring-4 structure (128x128, conflict-free swizzle,
// counted vmcnt) -- unchanged this round.
// ============================================================================

#define STAGE(t, b) do { \
    const bf16* Ag_ = Abase + (t)*32; \
    const bf16* Bg_ = Bbase + (t)*32; \
    GLL16(Ag_ + aoff0, As[b] + w*512); \
    GLL16(Ag_ + aoff1, As[b] + 2048 + w*512); \
    GLL16(Bg_ + aoff0, Bs[b] + w*512); \
    GLL16(Bg_ + aoff1, Bs[b] + 2048 + w*512); \
} while (0)

#define GEMM_MAINLOOP() \
    int tid = threadIdx.x, lane = tid & 63, w = tid >> 6; \
    int wm = w >> 1, wn = w & 1; \
    int srow = w*16 + (lane >> 2); \
    int scol = ((((lane & 3) - (srow >> 1)) & 3)) * 8; \
    long aoff0 = (long)srow * D_ + scol; \
    long aoff1 = aoff0 + 64L * D_; \
    f32x4 acc[4][4]; \
    _Pragma("unroll") \
    for (int i = 0; i < 4; ++i) \
        _Pragma("unroll") \
        for (int j = 0; j < 4; ++j) acc[i][j] = f32x4{0.f,0.f,0.f,0.f}; \
    STAGE(0, 0); STAGE(1, 1); STAGE(2, 2); \
    for (int kt = 0; kt < D_/32; ++kt) { \
        int rem = D_/32 - 1 - kt; \
        if (rem >= 2)      asm volatile("s_waitcnt vmcnt(8)" ::: "memory"); \
        else if (rem == 1) asm volatile("s_waitcnt vmcnt(4)" ::: "memory"); \
        else               asm volatile("s_waitcnt vmcnt(0)" ::: "memory"); \
        __builtin_amdgcn_s_barrier(); \
        asm volatile("" ::: "memory"); \
        int cb = kt & 3; \
        int g = lane >> 4; \
        bf16x8 af[4], bfr[4]; \
        _Pragma("unroll") \
        for (int mt = 0; mt < 4; ++mt) { \
            int r = wm*64 + mt*16 + (lane & 15); \
            af[mt] = *(const bf16x8*)&As[cb][r*32 + (((g + (r >> 1)) & 3) * 8)]; \
        } \
        _Pragma("unroll") \
        for (int nt = 0; nt < 4; ++nt) { \
            int r = wn*64 + nt*16 + (lane & 15); \
            bfr[nt] = *(const bf16x8*)&Bs[cb][r*32 + (((g + (r >> 1)) & 3) * 8)]; \
        } \
        if (kt + 3 < D_/32) { STAGE(kt + 3, (kt + 3) & 3); } \
        __builtin_amdgcn_s_setprio(1); \
        _Pragma("unroll") \
        for (int mt = 0; mt < 4; ++mt) \
            _Pragma("unroll") \
            for (int nt = 0; nt < 4; ++nt) \
                acc[mt][nt] = mfma16(af[mt], bfr[nt], acc[mt][nt]); \
        __builtin_amdgcn_s_setprio(0); \
    }

// ---------- causal flash attention, fixed-max softmax, K/V register prefetch ----------
// grid: 512 1-D blocks (heavy-first), block 256
__global__ __launch_bounds__(256) void attn(
    const bf16* __restrict__ Qm, const bf16* __restrict__ Km, const bf16* __restrict__ Vm,
    bf16* __restrict__ Om)   // Om in [B,T,D]
{
    __shared__ bf16 Ks[64*136];     // K tile [pos][d], +8 pad
    __shared__ bf16 Vt[128*72];     // V tile transposed Vt[d][pos], +8 pad
    __shared__ bf16 Ps[128*72];     // P round-trip (per-wave private rows)
    int bm = 15 - (blockIdx.x >> 5);        // heavy blocks dispatch first
    int bh = blockIdx.x & 31;
    int tid = threadIdx.x, lane = tid & 63, w = tid >> 6;
    const float c1 = 0.12754012780914427f;  // (1/sqrt(128)) * log2(e)
    const float c2 = 23.083120654223414f;   // 16 * log2(e)  (fixed max M=16)
    const bf16* Qb = Qm + (long)bh*T_*HD_;
    const bf16* Kb = Km + (long)bh*T_*HD_;
    const bf16* Vb = Vm + (long)bh*T_*HD_;
    int m0 = bm*128 + w*32;                 // this wave's 32 Q rows

    // Q fragments in regs for whole block
    bf16x8 qf[2][4];
    #pragma unroll
    for (int mt = 0; mt < 2; ++mt)
        #pragma unroll
        for (int ks = 0; ks < 4; ++ks)
            qf[mt][ks] = *(const bf16x8*)(Qb + (long)(m0 + mt*16 + (lane & 15))*HD_ + ks*32 + (lane >> 4)*8);

    // ones B-fragment: B[k][0]=1 -> row-sum of P rides the MFMA pipe
    bf16x8 onesB;
    {
        short v1 = ((lane & 15) == 0) ? (short)0x3F80 : (short)0;
        #pragma unroll
        for (int jj = 0; jj < 8; ++jj) onesB[jj] = v1;
    }

    f32x4 oacc[2][8];
    f32x4 lacc[2];
    #pragma unroll
    for (int mt = 0; mt < 2; ++mt) {
        lacc[mt] = f32x4{0.f,0.f,0.f,0.f};
        #pragma unroll
        for (int dt = 0; dt < 8; ++dt) oacc[mt][dt] = f32x4{0.f,0.f,0.f,0.f};
    }

    int krow = (tid >> 4);          // + i*16
    int kcg  = tid & 15;
    int njt = 2*bm + 2;             // causal: K/V tiles 0..2bm+1

    // prefetch tile 0 into regs
    bf16x8 kreg[4], vreg[4];
    #pragma unroll
    for (int i = 0; i < 4; ++i) {
        kreg[i] = *(const bf16x8*)(Kb + (long)(i*16 + krow)*HD_ + kcg*8);
        vreg[i] = *(const bf16x8*)(Vb + (long)lane*HD_ + (w + i*4)*8);
    }

    for (int j = 0; j < njt; ++j) {
        int j0 = j*64;
        __syncthreads();                         // all waves done reading prev Ks/Vt
        #pragma unroll
        for (int i = 0; i < 4; ++i)              // K regs -> LDS (vector)
            *(bf16x8*)&Ks[(i*16 + krow)*136 + kcg*8] = kreg[i];
        #pragma unroll
        for (int i = 0; i < 4; ++i) {            // V regs -> LDS transposed (scatter)
            int dg = w + i*4;
            union { bf16 h[8]; bf16x8 v; } u;
            u.v = vreg[i];
            #pragma unroll
            for (int jj = 0; jj < 8; ++jj)
                Vt[(dg*8 + jj)*72 + lane] = u.h[jj];
        }
        __syncthreads();

        // issue prefetch for tile j+1 (overlaps with compute below)
        if (j + 1 < njt) {
            int jn0 = j0 + 64;
            #pragma unroll
            for (int i = 0; i < 4; ++i) {
                kreg[i] = *(const bf16x8*)(Kb + (long)(jn0 + i*16 + krow)*HD_ + kcg*8);
                vreg[i] = *(const bf16x8*)(Vb + (long)(jn0 + lane)*HD_ + (w + i*4)*8);
            }
        }

        bool anyv  = (j0 <= m0 + 31);            // wave-uniform: any visible column?
        if (anyv) {
            bool bmask = (j0 + 63 > m0);         // wave-uniform: boundary tile?
            // S = Q K^T  (32 rows x 64 cols per wave)
            f32x4 s[2][4];
            #pragma unroll
            for (int mt = 0; mt < 2; ++mt)
                #pragma unroll
                for (int nt = 0; nt < 4; ++nt) s[mt][nt] = f32x4{0.f,0.f,0.f,0.f};
            #pragma unroll
            for (int ks = 0; ks < 4; ++ks) {
                bf16x8 kf[4];
                #pragma unroll
                for (int nt = 0; nt < 4; ++nt)
                    kf[nt] = *(const bf16x8*)&Ks[(nt*16 + (lane & 15))*136 + ks*32 + (lane >> 4)*8];
                #pragma unroll
                for (int mt = 0; mt < 2; ++mt)
                    #pragma unroll
                    for (int nt = 0; nt < 4; ++nt)
                        s[mt][nt] = mfma16(qf[mt][ks], kf[nt], s[mt][nt]);
            }
            // fixed-max softmax: p = exp2(s*c1 - c2); no reductions, no rescale
            #pragma unroll
            for (int mt = 0; mt < 2; ++mt) {
                #pragma unroll
                for (int nt = 0; nt < 4; ++nt) {
                    int n = j0 + nt*16 + (lane & 15);
                    #pragma unroll
                    for (int r = 0; r < 4; ++r) {
                        float x = s[mt][nt][r] * c1 - c2;
                        if (bmask) {
                            int mg = m0 + mt*16 + (lane >> 4)*4 + r;
                            x = (n <= mg) ? x : -1e30f;
                        }
                        float p = exp2f(x);
                        int prow = w*32 + mt*16 + (lane >> 4)*4 + r;
                        Ps[prow*72 + nt*16 + (lane & 15)] = __float2bfloat16(p);
                    }
                }
            }
            // O += P V ; l += P 1   (P via LDS C->A layout; V via Vt: ds_read_b128)
            #pragma unroll
            for (int kn = 0; kn < 2; ++kn) {
                bf16x8 pf[2], vf[8];
                #pragma unroll
                for (int mt = 0; mt < 2; ++mt)
                    pf[mt] = *(const bf16x8*)&Ps[(w*32 + mt*16 + (lane & 15))*72 + kn*32 + (lane >> 4)*8];
                #pragma unroll
                for (int dt = 0; dt < 8; ++dt)
                    vf[dt] = *(const bf16x8*)&Vt[(dt*16 + (lane & 15))*72 + kn*32 + (lane >> 4)*8];
                #pragma unroll
                for (int mt = 0; mt < 2; ++mt)
                    lacc[mt] = mfma16(pf[mt], onesB, lacc[mt]);
                #pragma unroll
                for (int mt = 0; mt < 2; ++mt)
                    #pragma unroll
                    for (int dt = 0; dt < 8; ++dt)
                        oacc[mt][dt] = mfma16(pf[mt], vf[dt], oacc[mt][dt]);
            }
        }
    }
    // epilogue: broadcast row sums (col 0 lives at lane&15==0), normalize, store
    int b = bh >> 4, h = bh & 15;
    #pragma unroll
    for (int mt = 0; mt < 2; ++mt) {
        #pragma unroll
        for (int r = 0; r < 4; ++r) {
            float l = __shfl(lacc[mt][r], lane & 48, 64);
            float inv = 1.f / l;
            int t = m0 + mt*16 + (lane >> 4)*4 + r;
            #pragma unroll
            for (int dt = 0; dt < 8; ++dt) {
                int d = dt*16 + (lane & 15);
                Om[((long)(b*T_ + t))*D_ + h*HD_ + d] = __float2bfloat16(oacc[mt][dt][r] * inv);
            }
        }
    }
}

// ---------- output projection: fp32 out = O @ Wo^T + bo ----------
__global__ __launch_bounds__(256) void gemm_out(
    const bf16* __restrict__ Ab, const bf16* __restrict__ Wob,
    const float* __restrict__ bo, float* __restrict__ out)
{
    __shared__ bf16 As[4][128*32];
    __shared__ bf16 Bs[4][128*32];
    int bn = blockIdx.x, bm = blockIdx.y;
    const bf16* Abase = Ab  + (long)bm * 128 * D_;
    const bf16* Bbase = Wob + (long)bn * 128 * D_;

    GEMM_MAINLOOP();

    int mlo = bm*128 + wm*64;
    int nlo = bn*128 + wn*64;
    #pragma unroll
    for (int mt = 0; mt < 4; ++mt) {
        #pragma unroll
        for (int nt = 0; nt < 4; ++nt) {
            int n = nlo + nt*16 + (lane & 15);
            float bias = bo[n];
            #pragma unroll
            for (int r = 0; r < 4; ++r) {
                int m = mlo + mt*16 + (lane >> 4)*4 + r;
                out[(long)m*D_ + n] = acc[mt][nt][r] + bias;
            }
        }
    }
}

extern "C" void kernel_launch(void* const* d_in, const int* in_sizes, int n_in,
                              void* d_out, int out_size, void* d_ws, size_t ws_size,
                              hipStream_t stream) {
    const float* x  = (const float*)d_in[0];
    const float* Wq = (const float*)d_in[1];
    const float* Wk = (const float*)d_in[2];
    const float* Wv = (const float*)d_in[3];
    const float* Wo = (const float*)d_in[4];
    const float* bo = (const float*)d_in[5];
    float* out = (float*)d_out;

    bf16* ws  = (bf16*)d_ws;
    bf16* xb  = ws;                    // 8388608 elems [B*T, D], later reused as attn output O
    bf16* wqb = ws + 8388608L;         // wq/wk/wv contiguous = Wall [6144][2048]
    bf16* wob = ws + 20971520L;
    bf16* Qb  = ws + 25165824L;        // [B,H,T,HD]; Q/K/V contiguous (8388608 each)
    bf16* Kb  = ws + 33554432L;
    bf16* Vb  = ws + 41943040L;
    bf16* Ob  = xb;                    // reuse (xb dead after gemm_qkv256)

    cast6<<<dim3(2048, 6), 256, 0, stream>>>(x, x + 4194304L, Wq, Wk, Wv, Wo, ws);
    gemm_qkv256<<<dim3(384), 512, 0, stream>>>(xb, wqb, Qb);
    attn<<<512, 256, 0, stream>>>(Qb, Kb, Vb, Ob);
    gemm_out<<<dim3(16, 32), 256, 0, stream>>>(Ob, wob, bo, out);
}

// Round 3
// 405.006 us; speedup vs baseline: 1.0248x; 1.0248x over previous
//
#include <hip/hip_runtime.h>
#include <hip/hip_bf16.h>

#define T_ 2048
#define D_ 2048
#define H_ 16
#define HD_ 128

typedef __hip_bfloat16 bf16;
using bf16x8 = __attribute__((ext_vector_type(8))) short;   // 8 bf16 = 4 VGPRs
using f32x4  = __attribute__((ext_vector_type(4))) float;

#define GLL16(g, l) __builtin_amdgcn_global_load_lds( \
    (const __attribute__((address_space(1))) void*)(g), \
    (__attribute__((address_space(3))) void*)(l), 16, 0, 0)

__device__ __forceinline__ f32x4 mfma16(bf16x8 a, bf16x8 b, f32x4 c) {
    return __builtin_amdgcn_mfma_f32_16x16x32_bf16(a, b, c, 0, 0, 0);
}

// ---------- cast fp32 -> bf16: 6 uniform chunks of 4194304 elems ----------
__global__ __launch_bounds__(256) void cast6(
    const float* __restrict__ s0, const float* __restrict__ s1,
    const float* __restrict__ s2, const float* __restrict__ s3,
    const float* __restrict__ s4, const float* __restrict__ s5,
    bf16* __restrict__ dst)
{
    int z = blockIdx.y;
    const float* s = (z == 0) ? s0 : (z == 1) ? s1 : (z == 2) ? s2
                   : (z == 3) ? s3 : (z == 4) ? s4 : s5;
    long i = ((long)blockIdx.x * 256 + threadIdx.x) * 8;
    float4 a = *(const float4*)(s + i);
    float4 b = *(const float4*)(s + i + 4);
    union { bf16 h[8]; int4 v; } u;
    u.h[0] = __float2bfloat16(a.x); u.h[1] = __float2bfloat16(a.y);
    u.h[2] = __float2bfloat16(a.z); u.h[3] = __float2bfloat16(a.w);
    u.h[4] = __float2bfloat16(b.x); u.h[5] = __float2bfloat16(b.y);
    u.h[6] = __float2bfloat16(b.z); u.h[7] = __float2bfloat16(b.w);
    *(int4*)(dst + (long)z * 4194304 + i) = u.v;
}

// ============================================================================
// QKV as ONE fused GEMM: C[4096][6144] = X[4096][2048] @ Wall[6144][2048]^T
// 256x256 tile, BK=64, 8 waves (2Mx4N), per-wave output 128x64.
// 8-phase schedule (T3+T4), T5 setprio around MFMA clusters.
// LDS swizzle (T2, FULL-SPREAD, fixed in r3): within each [*][64] row,
// 16B-slot index s is stored at physical slot s ^ (row & 7).
//   - fragment read: row = *16 + (lane&15), so row&7 = lane&7 -> the 64 lanes
//     cover all 8 slots uniformly (8 lanes/slot, 2-way/bank = free).
//   - staging: gload_lds dest stays LINEAR (HW rule); the involution is applied
//     by pre-swizzling the GLOBAL source column: thread (row=tid>>3, slot=tid&7)
//     fetches logical slot (tid&7)^((tid>>3)&7).
// r2's weak variant (col ^= ((row>>2)&1)<<4) only used banks 0-15 -> 9.4e6
// conflicts; this one is conflict-free by enumeration.
// Staging schedule (race-checked, unchanged from r2):
//   tile t phases stage: ph1 t+1.B0, ph2 t+1.B1 (opposite buffer), ph3 t+2.A0,
//   ph4 t+2.A1 (same buffer as t; A-half last ds_read is ph2, issue after ph2's
//   trailing barrier). vmcnt(4) at ph4 -> t+1 fully resident before its compute.
// ============================================================================

#define SA(t, h, b) do { \
    GLL16(Ab0 + (long)(h)*262144 + (t)*64,          &Asm[b][h][tid*8]); \
    GLL16(Ab0 + (long)(h)*262144 + 131072 + (t)*64, &Asm[b][h][4096 + tid*8]); \
} while (0)
#define SB(t, h, b) do { \
    GLL16(Bb0 + (long)(h)*262144 + (t)*64,          &Bsm[b][h][tid*8]); \
    GLL16(Bb0 + (long)(h)*262144 + 131072 + (t)*64, &Bsm[b][h][4096 + tid*8]); \
} while (0)

#define RA(mf, ks) (*(const bf16x8*)&Asm[buf][wr][((mf)*16 + l15)*64 + ((((ks)*32) + g8) ^ swF)])
#define RB(nf, ks) (*(const bf16x8*)&Bsm[buf][wc>>1][((wc&1)*64 + (nf)*16 + l15)*64 + ((((ks)*32) + g8) ^ swF)])

#define PH_SYNC() do { \
    __builtin_amdgcn_s_barrier(); \
    asm volatile("s_waitcnt lgkmcnt(0)" ::: "memory"); \
    __builtin_amdgcn_sched_barrier(0); \
} while (0)

__global__ __launch_bounds__(512) void gemm_qkv256(
    const bf16* __restrict__ xb, const bf16* __restrict__ Wall,
    bf16* __restrict__ QKV)   // 3 x [B,H,T,HD] contiguous
{
    __shared__ bf16 Asm[2][2][8192];   // [buf][half][128*64]
    __shared__ bf16 Bsm[2][2][8192];
    int tid = threadIdx.x, lane = tid & 63, wid = tid >> 6;
    int wr = wid >> 2, wc = wid & 3;
    // XCD-aware bijective swizzle (nwg = 384, 384 % 8 == 0)
    int orig = blockIdx.x;
    int wg = (orig & 7) * 48 + (orig >> 3);
    int bm = wg / 24, bn = wg - bm * 24;          // 16 x 24

    // staging: thread covers physical (row sr, slot tid&7) of a [128][64] half-tile
    // (and row sr+64; (sr+64)&7 == sr&7 so the same source column serves both).
    int sr  = tid >> 3;
    int sc  = (((tid & 7) ^ (sr & 7)) * 8);       // pre-swizzled source column
    const bf16* Ab0 = xb   + ((long)(bm * 256 + sr)) * 2048 + sc;
    const bf16* Bb0 = Wall + ((long)(bn * 256 + sr)) * 2048 + sc;

    // fragment-read constants
    int l15 = lane & 15, g8 = (lane >> 4) * 8;
    int swF = (l15 & 7) << 3;                     // row&7 == lane&7 for all frags

    f32x4 acc[8][4];
    #pragma unroll
    for (int i = 0; i < 8; ++i)
        #pragma unroll
        for (int j = 0; j < 4; ++j) acc[i][j] = f32x4{0.f, 0.f, 0.f, 0.f};

    bf16x8 Ar[8][2];   // [mf][ks]
    bf16x8 Br[4][2];   // [nf][ks]

    // prologue: t0 complete + t1 A-halves in flight
    SA(0, 0, 0); SA(0, 1, 0); SB(0, 0, 0); SB(0, 1, 0);
    SA(1, 0, 1); SA(1, 1, 1);
    asm volatile("s_waitcnt vmcnt(4)" ::: "memory");
    __builtin_amdgcn_s_barrier();

    const int NT = D_ / 64;   // 32
    for (int t = 0; t < NT; ++t) {
        int buf = t & 1, nbuf = buf ^ 1;
        // ---- phase 1: read A(mf0-3) + B(nf0-1); stage t+1.B0; MFMA q(0,0) ----
        #pragma unroll
        for (int mf = 0; mf < 4; ++mf) { Ar[mf][0] = RA(mf, 0); Ar[mf][1] = RA(mf, 1); }
        #pragma unroll
        for (int nf = 0; nf < 2; ++nf) { Br[nf][0] = RB(nf, 0); Br[nf][1] = RB(nf, 1); }
        if (t + 1 < NT) SB(t + 1, 0, nbuf);
        PH_SYNC();
        __builtin_amdgcn_s_setprio(1);
        #pragma unroll
        for (int mf = 0; mf < 4; ++mf)
            #pragma unroll
            for (int nf = 0; nf < 2; ++nf) {
                acc[mf][nf] = mfma16(Ar[mf][0], Br[nf][0], acc[mf][nf]);
                acc[mf][nf] = mfma16(Ar[mf][1], Br[nf][1], acc[mf][nf]);
            }
        __builtin_amdgcn_s_setprio(0);
        __builtin_amdgcn_s_barrier();
        // ---- phase 2: read A(mf4-7); stage t+1.B1; MFMA q(1,0) ----
        #pragma unroll
        for (int mf = 4; mf < 8; ++mf) { Ar[mf][0] = RA(mf, 0); Ar[mf][1] = RA(mf, 1); }
        if (t + 1 < NT) SB(t + 1, 1, nbuf);
        PH_SYNC();
        __builtin_amdgcn_s_setprio(1);
        #pragma unroll
        for (int mf = 4; mf < 8; ++mf)
            #pragma unroll
            for (int nf = 0; nf < 2; ++nf) {
                acc[mf][nf] = mfma16(Ar[mf][0], Br[nf][0], acc[mf][nf]);
                acc[mf][nf] = mfma16(Ar[mf][1], Br[nf][1], acc[mf][nf]);
            }
        __builtin_amdgcn_s_setprio(0);
        __builtin_amdgcn_s_barrier();
        // ---- phase 3: read B(nf2-3); stage t+2.A0 (A reads done at ph2); MFMA q(0,1) ----
        #pragma unroll
        for (int nf = 2; nf < 4; ++nf) { Br[nf][0] = RB(nf, 0); Br[nf][1] = RB(nf, 1); }
        if (t + 2 < NT) SA(t + 2, 0, buf);
        PH_SYNC();
        __builtin_amdgcn_s_setprio(1);
        #pragma unroll
        for (int mf = 0; mf < 4; ++mf)
            #pragma unroll
            for (int nf = 2; nf < 4; ++nf) {
                acc[mf][nf] = mfma16(Ar[mf][0], Br[nf][0], acc[mf][nf]);
                acc[mf][nf] = mfma16(Ar[mf][1], Br[nf][1], acc[mf][nf]);
            }
        __builtin_amdgcn_s_setprio(0);
        __builtin_amdgcn_s_barrier();
        // ---- phase 4: stage t+2.A1; vmcnt(4); MFMA q(1,1) ----
        if (t + 2 < NT) {
            SA(t + 2, 1, buf);
            asm volatile("s_waitcnt vmcnt(4)" ::: "memory");
        } else {
            asm volatile("s_waitcnt vmcnt(0)" ::: "memory");
        }
        __builtin_amdgcn_s_barrier();
        __builtin_amdgcn_s_setprio(1);
        #pragma unroll
        for (int mf = 4; mf < 8; ++mf)
            #pragma unroll
            for (int nf = 2; nf < 4; ++nf) {
                acc[mf][nf] = mfma16(Ar[mf][0], Br[nf][0], acc[mf][nf]);
                acc[mf][nf] = mfma16(Ar[mf][1], Br[nf][1], acc[mf][nf]);
            }
        __builtin_amdgcn_s_setprio(0);
        __builtin_amdgcn_s_barrier();
    }

    // epilogue: C[m][n], n in [0,6144) -> z = n>>11, h = (n&2047)>>7, hd = n&127
    int mBase = bm * 256 + wr * 128;
    int nBase = bn * 256 + wc * 64;
    #pragma unroll
    for (int mf = 0; mf < 8; ++mf) {
        #pragma unroll
        for (int nf = 0; nf < 4; ++nf) {
            int n = nBase + nf * 16 + l15;
            int z = n >> 11, n2 = n & 2047;
            int h = n2 >> 7, hd = n2 & 127;
            #pragma unroll
            for (int r = 0; r < 4; ++r) {
                int m = mBase + mf * 16 + (lane >> 4) * 4 + r;
                int b = m >> 11, tt = m & 2047;
                QKV[(long)z * 8388608 + (((long)(b * H_ + h)) * T_ + tt) * HD_ + hd] =
                    __float2bfloat16(acc[mf][nf][r]);
            }
        }
    }
}

// ============================================================================
// gemm_out keeps the round-1 ring-4 structure (128x128, conflict-free swizzle,
// counted vmcnt) -- unchanged this round.
// ============================================================================

#define STAGE(t, b) do { \
    const bf16* Ag_ = Abase + (t)*32; \
    const bf16* Bg_ = Bbase + (t)*32; \
    GLL16(Ag_ + aoff0, As[b] + w*512); \
    GLL16(Ag_ + aoff1, As[b] + 2048 + w*512); \
    GLL16(Bg_ + aoff0, Bs[b] + w*512); \
    GLL16(Bg_ + aoff1, Bs[b] + 2048 + w*512); \
} while (0)

#define GEMM_MAINLOOP() \
    int tid = threadIdx.x, lane = tid & 63, w = tid >> 6; \
    int wm = w >> 1, wn = w & 1; \
    int srow = w*16 + (lane >> 2); \
    int scol = ((((lane & 3) - (srow >> 1)) & 3)) * 8; \
    long aoff0 = (long)srow * D_ + scol; \
    long aoff1 = aoff0 + 64L * D_; \
    f32x4 acc[4][4]; \
    _Pragma("unroll") \
    for (int i = 0; i < 4; ++i) \
        _Pragma("unroll") \
        for (int j = 0; j < 4; ++j) acc[i][j] = f32x4{0.f,0.f,0.f,0.f}; \
    STAGE(0, 0); STAGE(1, 1); STAGE(2, 2); \
    for (int kt = 0; kt < D_/32; ++kt) { \
        int rem = D_/32 - 1 - kt; \
        if (rem >= 2)      asm volatile("s_waitcnt vmcnt(8)" ::: "memory"); \
        else if (rem == 1) asm volatile("s_waitcnt vmcnt(4)" ::: "memory"); \
        else               asm volatile("s_waitcnt vmcnt(0)" ::: "memory"); \
        __builtin_amdgcn_s_barrier(); \
        asm volatile("" ::: "memory"); \
        int cb = kt & 3; \
        int g = lane >> 4; \
        bf16x8 af[4], bfr[4]; \
        _Pragma("unroll") \
        for (int mt = 0; mt < 4; ++mt) { \
            int r = wm*64 + mt*16 + (lane & 15); \
            af[mt] = *(const bf16x8*)&As[cb][r*32 + (((g + (r >> 1)) & 3) * 8)]; \
        } \
        _Pragma("unroll") \
        for (int nt = 0; nt < 4; ++nt) { \
            int r = wn*64 + nt*16 + (lane & 15); \
            bfr[nt] = *(const bf16x8*)&Bs[cb][r*32 + (((g + (r >> 1)) & 3) * 8)]; \
        } \
        if (kt + 3 < D_/32) { STAGE(kt + 3, (kt + 3) & 3); } \
        __builtin_amdgcn_s_setprio(1); \
        _Pragma("unroll") \
        for (int mt = 0; mt < 4; ++mt) \
            _Pragma("unroll") \
            for (int nt = 0; nt < 4; ++nt) \
                acc[mt][nt] = mfma16(af[mt], bfr[nt], acc[mt][nt]); \
        __builtin_amdgcn_s_setprio(0); \
    }

// ---------- causal flash attention, fixed-max softmax, K/V register prefetch ----------
// grid: 512 1-D blocks (heavy-first), block 256
__global__ __launch_bounds__(256) void attn(
    const bf16* __restrict__ Qm, const bf16* __restrict__ Km, const bf16* __restrict__ Vm,
    bf16* __restrict__ Om)   // Om in [B,T,D]
{
    __shared__ bf16 Ks[64*136];     // K tile [pos][d], +8 pad
    __shared__ bf16 Vt[128*72];     // V tile transposed Vt[d][pos], +8 pad
    __shared__ bf16 Ps[128*72];     // P round-trip (per-wave private rows)
    int bm = 15 - (blockIdx.x >> 5);        // heavy blocks dispatch first
    int bh = blockIdx.x & 31;
    int tid = threadIdx.x, lane = tid & 63, w = tid >> 6;
    const float c1 = 0.12754012780914427f;  // (1/sqrt(128)) * log2(e)
    const float c2 = 23.083120654223414f;   // 16 * log2(e)  (fixed max M=16)
    const bf16* Qb = Qm + (long)bh*T_*HD_;
    const bf16* Kb = Km + (long)bh*T_*HD_;
    const bf16* Vb = Vm + (long)bh*T_*HD_;
    int m0 = bm*128 + w*32;                 // this wave's 32 Q rows

    // Q fragments in regs for whole block
    bf16x8 qf[2][4];
    #pragma unroll
    for (int mt = 0; mt < 2; ++mt)
        #pragma unroll
        for (int ks = 0; ks < 4; ++ks)
            qf[mt][ks] = *(const bf16x8*)(Qb + (long)(m0 + mt*16 + (lane & 15))*HD_ + ks*32 + (lane >> 4)*8);

    // ones B-fragment: B[k][0]=1 -> row-sum of P rides the MFMA pipe
    bf16x8 onesB;
    {
        short v1 = ((lane & 15) == 0) ? (short)0x3F80 : (short)0;
        #pragma unroll
        for (int jj = 0; jj < 8; ++jj) onesB[jj] = v1;
    }

    f32x4 oacc[2][8];
    f32x4 lacc[2];
    #pragma unroll
    for (int mt = 0; mt < 2; ++mt) {
        lacc[mt] = f32x4{0.f,0.f,0.f,0.f};
        #pragma unroll
        for (int dt = 0; dt < 8; ++dt) oacc[mt][dt] = f32x4{0.f,0.f,0.f,0.f};
    }

    int krow = (tid >> 4);          // + i*16
    int kcg  = tid & 15;
    int njt = 2*bm + 2;             // causal: K/V tiles 0..2bm+1

    // prefetch tile 0 into regs
    bf16x8 kreg[4], vreg[4];
    #pragma unroll
    for (int i = 0; i < 4; ++i) {
        kreg[i] = *(const bf16x8*)(Kb + (long)(i*16 + krow)*HD_ + kcg*8);
        vreg[i] = *(const bf16x8*)(Vb + (long)lane*HD_ + (w + i*4)*8);
    }

    for (int j = 0; j < njt; ++j) {
        int j0 = j*64;
        __syncthreads();                         // all waves done reading prev Ks/Vt
        #pragma unroll
        for (int i = 0; i < 4; ++i)              // K regs -> LDS (vector)
            *(bf16x8*)&Ks[(i*16 + krow)*136 + kcg*8] = kreg[i];
        #pragma unroll
        for (int i = 0; i < 4; ++i) {            // V regs -> LDS transposed (scatter)
            int dg = w + i*4;
            union { bf16 h[8]; bf16x8 v; } u;
            u.v = vreg[i];
            #pragma unroll
            for (int jj = 0; jj < 8; ++jj)
                Vt[(dg*8 + jj)*72 + lane] = u.h[jj];
        }
        __syncthreads();

        // issue prefetch for tile j+1 (overlaps with compute below)
        if (j + 1 < njt) {
            int jn0 = j0 + 64;
            #pragma unroll
            for (int i = 0; i < 4; ++i) {
                kreg[i] = *(const bf16x8*)(Kb + (long)(jn0 + i*16 + krow)*HD_ + kcg*8);
                vreg[i] = *(const bf16x8*)(Vb + (long)(jn0 + lane)*HD_ + (w + i*4)*8);
            }
        }

        bool anyv  = (j0 <= m0 + 31);            // wave-uniform: any visible column?
        if (anyv) {
            bool bmask = (j0 + 63 > m0);         // wave-uniform: boundary tile?
            // S = Q K^T  (32 rows x 64 cols per wave)
            f32x4 s[2][4];
            #pragma unroll
            for (int mt = 0; mt < 2; ++mt)
                #pragma unroll
                for (int nt = 0; nt < 4; ++nt) s[mt][nt] = f32x4{0.f,0.f,0.f,0.f};
            #pragma unroll
            for (int ks = 0; ks < 4; ++ks) {
                bf16x8 kf[4];
                #pragma unroll
                for (int nt = 0; nt < 4; ++nt)
                    kf[nt] = *(const bf16x8*)&Ks[(nt*16 + (lane & 15))*136 + ks*32 + (lane >> 4)*8];
                #pragma unroll
                for (int mt = 0; mt < 2; ++mt)
                    #pragma unroll
                    for (int nt = 0; nt < 4; ++nt)
                        s[mt][nt] = mfma16(qf[mt][ks], kf[nt], s[mt][nt]);
            }
            // fixed-max softmax: p = exp2(s*c1 - c2); no reductions, no rescale
            #pragma unroll
            for (int mt = 0; mt < 2; ++mt) {
                #pragma unroll
                for (int nt = 0; nt < 4; ++nt) {
                    int n = j0 + nt*16 + (lane & 15);
                    #pragma unroll
                    for (int r = 0; r < 4; ++r) {
                        float x = s[mt][nt][r] * c1 - c2;
                        if (bmask) {
                            int mg = m0 + mt*16 + (lane >> 4)*4 + r;
                            x = (n <= mg) ? x : -1e30f;
                        }
                        float p = exp2f(x);
                        int prow = w*32 + mt*16 + (lane >> 4)*4 + r;
                        Ps[prow*72 + nt*16 + (lane & 15)] = __float2bfloat16(p);
                    }
                }
            }
            // O += P V ; l += P 1   (P via LDS C->A layout; V via Vt: ds_read_b128)
            #pragma unroll
            for (int kn = 0; kn < 2; ++kn) {
                bf16x8 pf[2], vf[8];
                #pragma unroll
                for (int mt = 0; mt < 2; ++mt)
                    pf[mt] = *(const bf16x8*)&Ps[(w*32 + mt*16 + (lane & 15))*72 + kn*32 + (lane >> 4)*8];
                #pragma unroll
                for (int dt = 0; dt < 8; ++dt)
                    vf[dt] = *(const bf16x8*)&Vt[(dt*16 + (lane & 15))*72 + kn*32 + (lane >> 4)*8];
                #pragma unroll
                for (int mt = 0; mt < 2; ++mt)
                    lacc[mt] = mfma16(pf[mt], onesB, lacc[mt]);
                #pragma unroll
                for (int mt = 0; mt < 2; ++mt)
                    #pragma unroll
                    for (int dt = 0; dt < 8; ++dt)
                        oacc[mt][dt] = mfma16(pf[mt], vf[dt], oacc[mt][dt]);
            }
        }
    }
    // epilogue: broadcast row sums (col 0 lives at lane&15==0), normalize, store
    int b = bh >> 4, h = bh & 15;
    #pragma unroll
    for (int mt = 0; mt < 2; ++mt) {
        #pragma unroll
        for (int r = 0; r < 4; ++r) {
            float l = __shfl(lacc[mt][r], lane & 48, 64);
            float inv = 1.f / l;
            int t = m0 + mt*16 + (lane >> 4)*4 + r;
            #pragma unroll
            for (int dt = 0; dt < 8; ++dt) {
                int d = dt*16 + (lane & 15);
                Om[((long)(b*T_ + t))*D_ + h*HD_ + d] = __float2bfloat16(oacc[mt][dt][r] * inv);
            }
        }
    }
}

// ---------- output projection: fp32 out = O @ Wo^T + bo ----------
__global__ __launch_bounds__(256) void gemm_out(
    const bf16* __restrict__ Ab, const bf16* __restrict__ Wob,
    const float* __restrict__ bo, float* __restrict__ out)
{
    __shared__ bf16 As[4][128*32];
    __shared__ bf16 Bs[4][128*32];
    int bn = blockIdx.x, bm = blockIdx.y;
    const bf16* Abase = Ab  + (long)bm * 128 * D_;
    const bf16* Bbase = Wob + (long)bn * 128 * D_;

    GEMM_MAINLOOP();

    int mlo = bm*128 + wm*64;
    int nlo = bn*128 + wn*64;
    #pragma unroll
    for (int mt = 0; mt < 4; ++mt) {
        #pragma unroll
        for (int nt = 0; nt < 4; ++nt) {
            int n = nlo + nt*16 + (lane & 15);
            float bias = bo[n];
            #pragma unroll
            for (int r = 0; r < 4; ++r) {
                int m = mlo + mt*16 + (lane >> 4)*4 + r;
                out[(long)m*D_ + n] = acc[mt][nt][r] + bias;
            }
        }
    }
}

extern "C" void kernel_launch(void* const* d_in, const int* in_sizes, int n_in,
                              void* d_out, int out_size, void* d_ws, size_t ws_size,
                              hipStream_t stream) {
    const float* x  = (const float*)d_in[0];
    const float* Wq = (const float*)d_in[1];
    const float* Wk = (const float*)d_in[2];
    const float* Wv = (const float*)d_in[3];
    const float* Wo = (const float*)d_in[4];
    const float* bo = (const float*)d_in[5];
    float* out = (float*)d_out;

    bf16* ws  = (bf16*)d_ws;
    bf16* xb  = ws;                    // 8388608 elems [B*T, D], later reused as attn output O
    bf16* wqb = ws + 8388608L;         // wq/wk/wv contiguous = Wall [6144][2048]
    bf16* wob = ws + 20971520L;
    bf16* Qb  = ws + 25165824L;        // [B,H,T,HD]; Q/K/V contiguous (8388608 each)
    bf16* Kb  = ws + 33554432L;
    bf16* Vb  = ws + 41943040L;
    bf16* Ob  = xb;                    // reuse (xb dead after gemm_qkv256)

    cast6<<<dim3(2048, 6), 256, 0, stream>>>(x, x + 4194304L, Wq, Wk, Wv, Wo, ws);
    gemm_qkv256<<<dim3(384), 512, 0, stream>>>(xb, wqb, Qb);
    attn<<<512, 256, 0, stream>>>(Qb, Kb, Vb, Ob);
    gemm_out<<<dim3(16, 32), 256, 0, stream>>>(Ob, wob, bo, out);
}

// Round 5
// 399.774 us; speedup vs baseline: 1.0382x; 1.0131x over previous
//
#include <hip/hip_runtime.h>
#include <hip/hip_bf16.h>

#define T_ 2048
#define D_ 2048
#define H_ 16
#define HD_ 128

typedef __hip_bfloat16 bf16;
using bf16x8 = __attribute__((ext_vector_type(8))) short;   // 8 bf16 = 4 VGPRs
using f32x4  = __attribute__((ext_vector_type(4))) float;

#define GLL16(g, l) __builtin_amdgcn_global_load_lds( \
    (const __attribute__((address_space(1))) void*)(g), \
    (__attribute__((address_space(3))) void*)(l), 16, 0, 0)

__device__ __forceinline__ f32x4 mfma16(bf16x8 a, bf16x8 b, f32x4 c) {
    return __builtin_amdgcn_mfma_f32_16x16x32_bf16(a, b, c, 0, 0, 0);
}

// ---------- cast fp32 -> bf16: 6 uniform chunks of 4194304 elems ----------
__global__ __launch_bounds__(256) void cast6(
    const float* __restrict__ s0, const float* __restrict__ s1,
    const float* __restrict__ s2, const float* __restrict__ s3,
    const float* __restrict__ s4, const float* __restrict__ s5,
    bf16* __restrict__ dst)
{
    int z = blockIdx.y;
    const float* s = (z == 0) ? s0 : (z == 1) ? s1 : (z == 2) ? s2
                   : (z == 3) ? s3 : (z == 4) ? s4 : s5;
    long i = ((long)blockIdx.x * 256 + threadIdx.x) * 8;
    float4 a = *(const float4*)(s + i);
    float4 b = *(const float4*)(s + i + 4);
    union { bf16 h[8]; int4 v; } u;
    u.h[0] = __float2bfloat16(a.x); u.h[1] = __float2bfloat16(a.y);
    u.h[2] = __float2bfloat16(a.z); u.h[3] = __float2bfloat16(a.w);
    u.h[4] = __float2bfloat16(b.x); u.h[5] = __float2bfloat16(b.y);
    u.h[6] = __float2bfloat16(b.z); u.h[7] = __float2bfloat16(b.w);
    *(int4*)(dst + (long)z * 4194304 + i) = u.v;
}

// ============================================================================
// QKV fused GEMM: C[4096][6144] = X[4096][2048] @ Wall[6144][2048]^T
// Tile 128x384, BK=64 -> grid 32x16 = 512 blocks = exactly 2 full rounds.
// 8 waves (2M x 4N), per-wave output 64x96 (acc 4x6).
// r5 change vs r4 (crash retry): GLL16 LDS destination is now EXPLICITLY
// wave-uniform (wid*512 elems; HW adds lane*16B -> identical layout to r4's
// per-lane tid*8, but contract-exact per m104/m108). Nothing else changed.
// Swizzle (T2 full-spread, proven r3: conflicts = 0): physical 16B-slot p of
// row r holds logical slot p ^ (r&7); staging pre-swizzles the GLOBAL source
// column (gload_lds dest stays linear), reads XOR with (l15&7)<<3.
// Phase schedule per K-tile t:
//   ph1: read A[0-3]ks0 + B[0-2]ks0 ; stage B(t+1)c0,c1 -> nbuf ; MFMA {ks0,nf0-2}
//   ph2: read B[3-5]ks0             ; stage B(t+1)c2,c3 -> nbuf ; MFMA {ks0,nf3-5}
//   ph3: read A[0-3]ks1 + B[0-2]ks1 ; stage B(t+1)c4,c5 -> nbuf ; MFMA {ks1,nf0-2}
//   ph4: read B[3-5]ks1             ; stage A(t+2)c0,c1 -> buf  ; vmcnt(2); MFMA {ks1,nf3-5}
// Race check: B(t+1) -> opposite buffer (safe); A(t)'s last ds_read completes
// before ph3's trailing barrier -> A(t+2) into same buffer at ph4 is dead-safe.
// vmcnt(2) leaves only A(t+2) in flight -> t+1 resident before its compute.
// K-order per output elem unchanged (ks0,ks1 per tile) -> bit-identical absmax.
// ============================================================================

#define SA2(t, c, b) GLL16(Ab0 + (long)(c)*131072 + (t)*64, &Asm[b][c][wu])
#define SB2(t, c, b) GLL16(Bb0 + (long)(c)*131072 + (t)*64, &Bsm[b][c][wu])

#define RA2(mf, ks) (*(const bf16x8*)&Asm[buf][wr][((mf)*16 + l15)*64 + ((((ks)*32) + g8) ^ swF)])
#define RB2(nf, ks) (*(const bf16x8*)&Bsm[buf][(wc*96 + (nf)*16) >> 6][(((wc*96 + (nf)*16) & 63) + l15)*64 + ((((ks)*32) + g8) ^ swF)])

#define PH_SYNC() do { \
    __builtin_amdgcn_s_barrier(); \
    asm volatile("s_waitcnt lgkmcnt(0)" ::: "memory"); \
    __builtin_amdgcn_sched_barrier(0); \
} while (0)

__global__ __launch_bounds__(512) void gemm_qkv384(
    const bf16* __restrict__ xb, const bf16* __restrict__ Wall,
    bf16* __restrict__ QKV)   // 3 x [B,H,T,HD] contiguous
{
    __shared__ bf16 Asm[2][2][4096];   // [buf][64-row chunk][64*64]
    __shared__ bf16 Bsm[2][6][4096];   // [buf][64-row chunk][64*64]  (total 128 KiB)
    int tid = threadIdx.x, lane = tid & 63, wid = tid >> 6;
    int wr = wid >> 2, wc = wid & 3;              // 2M x 4N waves
    int wu = wid * 512;                           // wave-uniform LDS dest (elems)
    // XCD-aware bijective swizzle (nwg = 512, 512 % 8 == 0)
    int orig = blockIdx.x;
    int wg = (orig & 7) * 64 + (orig >> 3);
    int bm = wg >> 4, bn = wg & 15;               // 32 x 16

    // staging: thread covers (row sr, phys slot tid&7) of a 64x64 chunk
    int sr  = tid >> 3;                           // 0..63
    int sc  = (((tid & 7) ^ (sr & 7)) * 8);       // pre-swizzled source column
    const bf16* Ab0 = xb   + ((long)(bm * 128 + sr)) * 2048 + sc;
    const bf16* Bb0 = Wall + ((long)(bn * 384 + sr)) * 2048 + sc;

    // fragment-read constants (row&7 == l15&7 for every fragment row)
    int l15 = lane & 15, g8 = (lane >> 4) * 8;
    int swF = (l15 & 7) << 3;

    f32x4 acc[4][6];
    #pragma unroll
    for (int i = 0; i < 4; ++i)
        #pragma unroll
        for (int j = 0; j < 6; ++j) acc[i][j] = f32x4{0.f, 0.f, 0.f, 0.f};

    bf16x8 Ar0[4], Ar1[4];   // A frags ks0 / ks1
    bf16x8 Br[3];            // B frags, per phase

    // prologue: tile0 complete + tile1 A-chunks in flight
    SA2(0, 0, 0); SA2(0, 1, 0);
    SB2(0, 0, 0); SB2(0, 1, 0); SB2(0, 2, 0);
    SB2(0, 3, 0); SB2(0, 4, 0); SB2(0, 5, 0);
    SA2(1, 0, 1); SA2(1, 1, 1);
    asm volatile("s_waitcnt vmcnt(2)" ::: "memory");
    __builtin_amdgcn_s_barrier();

    const int NT = D_ / 64;   // 32
    for (int t = 0; t < NT; ++t) {
        int buf = t & 1, nbuf = buf ^ 1;
        // ---- ph1: A[0-3]ks0 + B[0-2]ks0 ; stage B(t+1)c0,c1 ; MFMA {ks0,nf0-2} ----
        #pragma unroll
        for (int mf = 0; mf < 4; ++mf) Ar0[mf] = RA2(mf, 0);
        #pragma unroll
        for (int nf = 0; nf < 3; ++nf) Br[nf] = RB2(nf, 0);
        if (t + 1 < NT) { SB2(t + 1, 0, nbuf); SB2(t + 1, 1, nbuf); }
        PH_SYNC();
        __builtin_amdgcn_s_setprio(1);
        #pragma unroll
        for (int mf = 0; mf < 4; ++mf)
            #pragma unroll
            for (int nf = 0; nf < 3; ++nf)
                acc[mf][nf] = mfma16(Ar0[mf], Br[nf], acc[mf][nf]);
        __builtin_amdgcn_s_setprio(0);
        __builtin_amdgcn_s_barrier();
        // ---- ph2: B[3-5]ks0 ; stage B(t+1)c2,c3 ; MFMA {ks0,nf3-5} ----
        #pragma unroll
        for (int nf = 0; nf < 3; ++nf) Br[nf] = RB2(nf + 3, 0);
        if (t + 1 < NT) { SB2(t + 1, 2, nbuf); SB2(t + 1, 3, nbuf); }
        PH_SYNC();
        __builtin_amdgcn_s_setprio(1);
        #pragma unroll
        for (int mf = 0; mf < 4; ++mf)
            #pragma unroll
            for (int nf = 0; nf < 3; ++nf)
                acc[mf][nf + 3] = mfma16(Ar0[mf], Br[nf], acc[mf][nf + 3]);
        __builtin_amdgcn_s_setprio(0);
        __builtin_amdgcn_s_barrier();
        // ---- ph3: A[0-3]ks1 + B[0-2]ks1 ; stage B(t+1)c4,c5 ; MFMA {ks1,nf0-2} ----
        #pragma unroll
        for (int mf = 0; mf < 4; ++mf) Ar1[mf] = RA2(mf, 1);
        #pragma unroll
        for (int nf = 0; nf < 3; ++nf) Br[nf] = RB2(nf, 1);
        if (t + 1 < NT) { SB2(t + 1, 4, nbuf); SB2(t + 1, 5, nbuf); }
        PH_SYNC();
        __builtin_amdgcn_s_setprio(1);
        #pragma unroll
        for (int mf = 0; mf < 4; ++mf)
            #pragma unroll
            for (int nf = 0; nf < 3; ++nf)
                acc[mf][nf] = mfma16(Ar1[mf], Br[nf], acc[mf][nf]);
        __builtin_amdgcn_s_setprio(0);
        __builtin_amdgcn_s_barrier();
        // ---- ph4: B[3-5]ks1 ; stage A(t+2)c0,c1 ; vmcnt(2) ; MFMA {ks1,nf3-5} ----
        #pragma unroll
        for (int nf = 0; nf < 3; ++nf) Br[nf] = RB2(nf + 3, 1);
        if (t + 2 < NT) {
            SA2(t + 2, 0, buf); SA2(t + 2, 1, buf);
            asm volatile("s_waitcnt vmcnt(2)" ::: "memory");
        } else {
            asm volatile("s_waitcnt vmcnt(0)" ::: "memory");
        }
        PH_SYNC();
        __builtin_amdgcn_s_setprio(1);
        #pragma unroll
        for (int mf = 0; mf < 4; ++mf)
            #pragma unroll
            for (int nf = 0; nf < 3; ++nf)
                acc[mf][nf + 3] = mfma16(Ar1[mf], Br[nf], acc[mf][nf + 3]);
        __builtin_amdgcn_s_setprio(0);
        __builtin_amdgcn_s_barrier();
    }

    // epilogue: C[m][n], n in [0,6144) -> z = n>>11, h = (n&2047)>>7, hd = n&127
    int mBase = bm * 128 + wr * 64;
    int nBase = bn * 384 + wc * 96;
    #pragma unroll
    for (int mf = 0; mf < 4; ++mf) {
        #pragma unroll
        for (int nf = 0; nf < 6; ++nf) {
            int n = nBase + nf * 16 + l15;
            int z = n >> 11, n2 = n & 2047;
            int h = n2 >> 7, hd = n2 & 127;
            #pragma unroll
            for (int r = 0; r < 4; ++r) {
                int m = mBase + mf * 16 + (lane >> 4) * 4 + r;
                int b = m >> 11, tt = m & 2047;
                QKV[(long)z * 8388608 + (((long)(b * H_ + h)) * T_ + tt) * HD_ + hd] =
                    __float2bfloat16(acc[mf][nf][r]);
            }
        }
    }
}

// ============================================================================
// gemm_out keeps the round-1 ring-4 structure (128x128, conflict-free swizzle,
// counted vmcnt) -- unchanged.
// ============================================================================

#define STAGE(t, b) do { \
    const bf16* Ag_ = Abase + (t)*32; \
    const bf16* Bg_ = Bbase + (t)*32; \
    GLL16(Ag_ + aoff0, As[b] + w*512); \
    GLL16(Ag_ + aoff1, As[b] + 2048 + w*512); \
    GLL16(Bg_ + aoff0, Bs[b] + w*512); \
    GLL16(Bg_ + aoff1, Bs[b] + 2048 + w*512); \
} while (0)

#define GEMM_MAINLOOP() \
    int tid = threadIdx.x, lane = tid & 63, w = tid >> 6; \
    int wm = w >> 1, wn = w & 1; \
    int srow = w*16 + (lane >> 2); \
    int scol = ((((lane & 3) - (srow >> 1)) & 3)) * 8; \
    long aoff0 = (long)srow * D_ + scol; \
    long aoff1 = aoff0 + 64L * D_; \
    f32x4 acc[4][4]; \
    _Pragma("unroll") \
    for (int i = 0; i < 4; ++i) \
        _Pragma("unroll") \
        for (int j = 0; j < 4; ++j) acc[i][j] = f32x4{0.f,0.f,0.f,0.f}; \
    STAGE(0, 0); STAGE(1, 1); STAGE(2, 2); \
    for (int kt = 0; kt < D_/32; ++kt) { \
        int rem = D_/32 - 1 - kt; \
        if (rem >= 2)      asm volatile("s_waitcnt vmcnt(8)" ::: "memory"); \
        else if (rem == 1) asm volatile("s_waitcnt vmcnt(4)" ::: "memory"); \
        else               asm volatile("s_waitcnt vmcnt(0)" ::: "memory"); \
        __builtin_amdgcn_s_barrier(); \
        asm volatile("" ::: "memory"); \
        int cb = kt & 3; \
        int g = lane >> 4; \
        bf16x8 af[4], bfr[4]; \
        _Pragma("unroll") \
        for (int mt = 0; mt < 4; ++mt) { \
            int r = wm*64 + mt*16 + (lane & 15); \
            af[mt] = *(const bf16x8*)&As[cb][r*32 + (((g + (r >> 1)) & 3) * 8)]; \
        } \
        _Pragma("unroll") \
        for (int nt = 0; nt < 4; ++nt) { \
            int r = wn*64 + nt*16 + (lane & 15); \
            bfr[nt] = *(const bf16x8*)&Bs[cb][r*32 + (((g + (r >> 1)) & 3) * 8)]; \
        } \
        if (kt + 3 < D_/32) { STAGE(kt + 3, (kt + 3) & 3); } \
        __builtin_amdgcn_s_setprio(1); \
        _Pragma("unroll") \
        for (int mt = 0; mt < 4; ++mt) \
            _Pragma("unroll") \
            for (int nt = 0; nt < 4; ++nt) \
                acc[mt][nt] = mfma16(af[mt], bfr[nt], acc[mt][nt]); \
        __builtin_amdgcn_s_setprio(0); \
    }

// ---------- causal flash attention, fixed-max softmax, K/V register prefetch ----------
// grid: 512 1-D blocks (heavy-first), block 256
__global__ __launch_bounds__(256) void attn(
    const bf16* __restrict__ Qm, const bf16* __restrict__ Km, const bf16* __restrict__ Vm,
    bf16* __restrict__ Om)   // Om in [B,T,D]
{
    __shared__ bf16 Ks[64*136];     // K tile [pos][d], +8 pad
    __shared__ bf16 Vt[128*72];     // V tile transposed Vt[d][pos], +8 pad
    __shared__ bf16 Ps[128*72];     // P round-trip (per-wave private rows)
    int bm = 15 - (blockIdx.x >> 5);        // heavy blocks dispatch first
    int bh = blockIdx.x & 31;
    int tid = threadIdx.x, lane = tid & 63, w = tid >> 6;
    const float c1 = 0.12754012780914427f;  // (1/sqrt(128)) * log2(e)
    const float c2 = 23.083120654223414f;   // 16 * log2(e)  (fixed max M=16)
    const bf16* Qb = Qm + (long)bh*T_*HD_;
    const bf16* Kb = Km + (long)bh*T_*HD_;
    const bf16* Vb = Vm + (long)bh*T_*HD_;
    int m0 = bm*128 + w*32;                 // this wave's 32 Q rows

    // Q fragments in regs for whole block
    bf16x8 qf[2][4];
    #pragma unroll
    for (int mt = 0; mt < 2; ++mt)
        #pragma unroll
        for (int ks = 0; ks < 4; ++ks)
            qf[mt][ks] = *(const bf16x8*)(Qb + (long)(m0 + mt*16 + (lane & 15))*HD_ + ks*32 + (lane >> 4)*8);

    // ones B-fragment: B[k][0]=1 -> row-sum of P rides the MFMA pipe
    bf16x8 onesB;
    {
        short v1 = ((lane & 15) == 0) ? (short)0x3F80 : (short)0;
        #pragma unroll
        for (int jj = 0; jj < 8; ++jj) onesB[jj] = v1;
    }

    f32x4 oacc[2][8];
    f32x4 lacc[2];
    #pragma unroll
    for (int mt = 0; mt < 2; ++mt) {
        lacc[mt] = f32x4{0.f,0.f,0.f,0.f};
        #pragma unroll
        for (int dt = 0; dt < 8; ++dt) oacc[mt][dt] = f32x4{0.f,0.f,0.f,0.f};
    }

    int krow = (tid >> 4);          // + i*16
    int kcg  = tid & 15;
    int njt = 2*bm + 2;             // causal: K/V tiles 0..2bm+1

    // prefetch tile 0 into regs
    bf16x8 kreg[4], vreg[4];
    #pragma unroll
    for (int i = 0; i < 4; ++i) {
        kreg[i] = *(const bf16x8*)(Kb + (long)(i*16 + krow)*HD_ + kcg*8);
        vreg[i] = *(const bf16x8*)(Vb + (long)lane*HD_ + (w + i*4)*8);
    }

    for (int j = 0; j < njt; ++j) {
        int j0 = j*64;
        __syncthreads();                         // all waves done reading prev Ks/Vt
        #pragma unroll
        for (int i = 0; i < 4; ++i)              // K regs -> LDS (vector)
            *(bf16x8*)&Ks[(i*16 + krow)*136 + kcg*8] = kreg[i];
        #pragma unroll
        for (int i = 0; i < 4; ++i) {            // V regs -> LDS transposed (scatter)
            int dg = w + i*4;
            union { bf16 h[8]; bf16x8 v; } u;
            u.v = vreg[i];
            #pragma unroll
            for (int jj = 0; jj < 8; ++jj)
                Vt[(dg*8 + jj)*72 + lane] = u.h[jj];
        }
        __syncthreads();

        // issue prefetch for tile j+1 (overlaps with compute below)
        if (j + 1 < njt) {
            int jn0 = j0 + 64;
            #pragma unroll
            for (int i = 0; i < 4; ++i) {
                kreg[i] = *(const bf16x8*)(Kb + (long)(jn0 + i*16 + krow)*HD_ + kcg*8);
                vreg[i] = *(const bf16x8*)(Vb + (long)(jn0 + lane)*HD_ + (w + i*4)*8);
            }
        }

        bool anyv  = (j0 <= m0 + 31);            // wave-uniform: any visible column?
        if (anyv) {
            bool bmask = (j0 + 63 > m0);         // wave-uniform: boundary tile?
            // S = Q K^T  (32 rows x 64 cols per wave)
            f32x4 s[2][4];
            #pragma unroll
            for (int mt = 0; mt < 2; ++mt)
                #pragma unroll
                for (int nt = 0; nt < 4; ++nt) s[mt][nt] = f32x4{0.f,0.f,0.f,0.f};
            #pragma unroll
            for (int ks = 0; ks < 4; ++ks) {
                bf16x8 kf[4];
                #pragma unroll
                for (int nt = 0; nt < 4; ++nt)
                    kf[nt] = *(const bf16x8*)&Ks[(nt*16 + (lane & 15))*136 + ks*32 + (lane >> 4)*8];
                #pragma unroll
                for (int mt = 0; mt < 2; ++mt)
                    #pragma unroll
                    for (int nt = 0; nt < 4; ++nt)
                        s[mt][nt] = mfma16(qf[mt][ks], kf[nt], s[mt][nt]);
            }
            // fixed-max softmax: p = exp2(s*c1 - c2); no reductions, no rescale
            #pragma unroll
            for (int mt = 0; mt < 2; ++mt) {
                #pragma unroll
                for (int nt = 0; nt < 4; ++nt) {
                    int n = j0 + nt*16 + (lane & 15);
                    #pragma unroll
                    for (int r = 0; r < 4; ++r) {
                        float x = s[mt][nt][r] * c1 - c2;
                        if (bmask) {
                            int mg = m0 + mt*16 + (lane >> 4)*4 + r;
                            x = (n <= mg) ? x : -1e30f;
                        }
                        float p = exp2f(x);
                        int prow = w*32 + mt*16 + (lane >> 4)*4 + r;
                        Ps[prow*72 + nt*16 + (lane & 15)] = __float2bfloat16(p);
                    }
                }
            }
            // O += P V ; l += P 1   (P via LDS C->A layout; V via Vt: ds_read_b128)
            #pragma unroll
            for (int kn = 0; kn < 2; ++kn) {
                bf16x8 pf[2], vf[8];
                #pragma unroll
                for (int mt = 0; mt < 2; ++mt)
                    pf[mt] = *(const bf16x8*)&Ps[(w*32 + mt*16 + (lane & 15))*72 + kn*32 + (lane >> 4)*8];
                #pragma unroll
                for (int dt = 0; dt < 8; ++dt)
                    vf[dt] = *(const bf16x8*)&Vt[(dt*16 + (lane & 15))*72 + kn*32 + (lane >> 4)*8];
                #pragma unroll
                for (int mt = 0; mt < 2; ++mt)
                    lacc[mt] = mfma16(pf[mt], onesB, lacc[mt]);
                #pragma unroll
                for (int mt = 0; mt < 2; ++mt)
                    #pragma unroll
                    for (int dt = 0; dt < 8; ++dt)
                        oacc[mt][dt] = mfma16(pf[mt], vf[dt], oacc[mt][dt]);
            }
        }
    }
    // epilogue: broadcast row sums (col 0 lives at lane&15==0), normalize, store
    int b = bh >> 4, h = bh & 15;
    #pragma unroll
    for (int mt = 0; mt < 2; ++mt) {
        #pragma unroll
        for (int r = 0; r < 4; ++r) {
            float l = __shfl(lacc[mt][r], lane & 48, 64);
            float inv = 1.f / l;
            int t = m0 + mt*16 + (lane >> 4)*4 + r;
            #pragma unroll
            for (int dt = 0; dt < 8; ++dt) {
                int d = dt*16 + (lane & 15);
                Om[((long)(b*T_ + t))*D_ + h*HD_ + d] = __float2bfloat16(oacc[mt][dt][r] * inv);
            }
        }
    }
}

// ---------- output projection: fp32 out = O @ Wo^T + bo ----------
__global__ __launch_bounds__(256) void gemm_out(
    const bf16* __restrict__ Ab, const bf16* __restrict__ Wob,
    const float* __restrict__ bo, float* __restrict__ out)
{
    __shared__ bf16 As[4][128*32];
    __shared__ bf16 Bs[4][128*32];
    int bn = blockIdx.x, bm = blockIdx.y;
    const bf16* Abase = Ab  + (long)bm * 128 * D_;
    const bf16* Bbase = Wob + (long)bn * 128 * D_;

    GEMM_MAINLOOP();

    int mlo = bm*128 + wm*64;
    int nlo = bn*128 + wn*64;
    #pragma unroll
    for (int mt = 0; mt < 4; ++mt) {
        #pragma unroll
        for (int nt = 0; nt < 4; ++nt) {
            int n = nlo + nt*16 + (lane & 15);
            float bias = bo[n];
            #pragma unroll
            for (int r = 0; r < 4; ++r) {
                int m = mlo + mt*16 + (lane >> 4)*4 + r;
                out[(long)m*D_ + n] = acc[mt][nt][r] + bias;
            }
        }
    }
}

extern "C" void kernel_launch(void* const* d_in, const int* in_sizes, int n_in,
                              void* d_out, int out_size, void* d_ws, size_t ws_size,
                              hipStream_t stream) {
    const float* x  = (const float*)d_in[0];
    const float* Wq = (const float*)d_in[1];
    const float* Wk = (const float*)d_in[2];
    const float* Wv = (const float*)d_in[3];
    const float* Wo = (const float*)d_in[4];
    const float* bo = (const float*)d_in[5];
    float* out = (float*)d_out;

    bf16* ws  = (bf16*)d_ws;
    bf16* xb  = ws;                    // 8388608 elems [B*T, D], later reused as attn output O
    bf16* wqb = ws + 8388608L;         // wq/wk/wv contiguous = Wall [6144][2048]
    bf16* wob = ws + 20971520L;
    bf16* Qb  = ws + 25165824L;        // [B,H,T,HD]; Q/K/V contiguous (8388608 each)
    bf16* Kb  = ws + 33554432L;
    bf16* Vb  = ws + 41943040L;
    bf16* Ob  = xb;                    // reuse (xb dead after gemm_qkv384)

    cast6<<<dim3(2048, 6), 256, 0, stream>>>(x, x + 4194304L, Wq, Wk, Wv, Wo, ws);
    gemm_qkv384<<<dim3(512), 512, 0, stream>>>(xb, wqb, Qb);
    attn<<<512, 256, 0, stream>>>(Qb, Kb, Vb, Ob);
    gemm_out<<<dim3(16, 32), 256, 0, stream>>>(Ob, wob, bo, out);
}

// Round 6
// 388.402 us; speedup vs baseline: 1.0686x; 1.0293x over previous
//
#include <hip/hip_runtime.h>
#include <hip/hip_bf16.h>

#define T_ 2048
#define D_ 2048
#define H_ 16
#define HD_ 128

typedef __hip_bfloat16 bf16;
using bf16x8 = __attribute__((ext_vector_type(8))) short;   // 8 bf16 = 4 VGPRs
using f32x4  = __attribute__((ext_vector_type(4))) float;

#define GLL16(g, l) __builtin_amdgcn_global_load_lds( \
    (const __attribute__((address_space(1))) void*)(g), \
    (__attribute__((address_space(3))) void*)(l), 16, 0, 0)

__device__ __forceinline__ f32x4 mfma16(bf16x8 a, bf16x8 b, f32x4 c) {
    return __builtin_amdgcn_mfma_f32_16x16x32_bf16(a, b, c, 0, 0, 0);
}

// ---------- cast fp32 -> bf16: 6 uniform chunks of 4194304 elems ----------
__global__ __launch_bounds__(256) void cast6(
    const float* __restrict__ s0, const float* __restrict__ s1,
    const float* __restrict__ s2, const float* __restrict__ s3,
    const float* __restrict__ s4, const float* __restrict__ s5,
    bf16* __restrict__ dst)
{
    int z = blockIdx.y;
    const float* s = (z == 0) ? s0 : (z == 1) ? s1 : (z == 2) ? s2
                   : (z == 3) ? s3 : (z == 4) ? s4 : s5;
    long i = ((long)blockIdx.x * 256 + threadIdx.x) * 8;
    float4 a = *(const float4*)(s + i);
    float4 b = *(const float4*)(s + i + 4);
    union { bf16 h[8]; int4 v; } u;
    u.h[0] = __float2bfloat16(a.x); u.h[1] = __float2bfloat16(a.y);
    u.h[2] = __float2bfloat16(a.z); u.h[3] = __float2bfloat16(a.w);
    u.h[4] = __float2bfloat16(b.x); u.h[5] = __float2bfloat16(b.y);
    u.h[6] = __float2bfloat16(b.z); u.h[7] = __float2bfloat16(b.w);
    *(int4*)(dst + (long)z * 4194304 + i) = u.v;
}

// ============================================================================
// GEMM main loop: 128x128 tile, BK=32, RING-3 LDS buffers (r6: was ring-4).
// 48 KiB LDS -> 3 blocks/CU (12 waves) vs ring-4's 2 (8 waves).
// Schedule: stage tile kt+2 into buf[(kt+2)%3] while computing tile kt.
//   buf[(kt+2)%3] == buf[(kt-1)%3]: its last ds_reads completed before the
//   readers' MFMAs at tile kt-1, and ALL waves passed the kt barrier before
//   any stage issues -> dead at issue (race-free).
// vmcnt(4) at top of tile kt: outstanding = {kt:4, kt+1:4}; FIFO retirement
// (m135) -> waits exactly tile kt. Tail: vmcnt(0) at kt = NT-1.
// Conflict-free chunk swizzle (r1-proven, SQ_LDS_BANK_CONFLICT = 0):
//   stored chunk c holds k-group g = (c - (row>>1)) & 3, applied via
//   pre-swizzled GLOBAL source column (gload_lds dest stays linear).
// K-accumulation order identical to ring-4 -> bit-identical output.
// ============================================================================

#define STAGE(t, b) do { \
    const bf16* Ag_ = Abase + (t)*32; \
    const bf16* Bg_ = Bbase + (t)*32; \
    GLL16(Ag_ + aoff0, As[b] + w*512); \
    GLL16(Ag_ + aoff1, As[b] + 2048 + w*512); \
    GLL16(Bg_ + aoff0, Bs[b] + w*512); \
    GLL16(Bg_ + aoff1, Bs[b] + 2048 + w*512); \
} while (0)

#define GEMM_MAINLOOP() \
    int tid = threadIdx.x, lane = tid & 63, w = tid >> 6; \
    int wm = w >> 1, wn = w & 1; \
    int srow = w*16 + (lane >> 2); \
    int scol = ((((lane & 3) - (srow >> 1)) & 3)) * 8; \
    long aoff0 = (long)srow * D_ + scol; \
    long aoff1 = aoff0 + 64L * D_; \
    f32x4 acc[4][4]; \
    _Pragma("unroll") \
    for (int i = 0; i < 4; ++i) \
        _Pragma("unroll") \
        for (int j = 0; j < 4; ++j) acc[i][j] = f32x4{0.f,0.f,0.f,0.f}; \
    STAGE(0, 0); STAGE(1, 1); \
    int rb = 0, sb = 2; \
    for (int kt = 0; kt < D_/32; ++kt) { \
        if (kt + 1 < D_/32) asm volatile("s_waitcnt vmcnt(4)" ::: "memory"); \
        else                asm volatile("s_waitcnt vmcnt(0)" ::: "memory"); \
        __builtin_amdgcn_s_barrier(); \
        asm volatile("" ::: "memory"); \
        int g = lane >> 4; \
        bf16x8 af[4], bfr[4]; \
        _Pragma("unroll") \
        for (int mt = 0; mt < 4; ++mt) { \
            int r = wm*64 + mt*16 + (lane & 15); \
            af[mt] = *(const bf16x8*)&As[rb][r*32 + (((g + (r >> 1)) & 3) * 8)]; \
        } \
        _Pragma("unroll") \
        for (int nt = 0; nt < 4; ++nt) { \
            int r = wn*64 + nt*16 + (lane & 15); \
            bfr[nt] = *(const bf16x8*)&Bs[rb][r*32 + (((g + (r >> 1)) & 3) * 8)]; \
        } \
        if (kt + 2 < D_/32) { STAGE(kt + 2, sb); } \
        __builtin_amdgcn_s_setprio(1); \
        _Pragma("unroll") \
        for (int mt = 0; mt < 4; ++mt) \
            _Pragma("unroll") \
            for (int nt = 0; nt < 4; ++nt) \
                acc[mt][nt] = mfma16(af[mt], bfr[nt], acc[mt][nt]); \
        __builtin_amdgcn_s_setprio(0); \
        rb = (rb == 2) ? 0 : rb + 1; \
        sb = (sb == 2) ? 0 : sb + 1; \
    }

// ---------- QKV projection: C[m][n] = sum_k xb[m][k]*W[n][k], out -> [B,H,T,HD] bf16 ----------
__global__ __launch_bounds__(256) void gemm_qkv(
    const bf16* __restrict__ xb,
    const bf16* __restrict__ wq, const bf16* __restrict__ wk, const bf16* __restrict__ wv,
    bf16* __restrict__ Qo, bf16* __restrict__ Ko, bf16* __restrict__ Vo)
{
    __shared__ bf16 As[3][128*32];
    __shared__ bf16 Bs[3][128*32];
    int z = blockIdx.z;
    const bf16* W = (z == 0) ? wq : (z == 1) ? wk : wv;
    bf16* out = (z == 0) ? Qo : (z == 1) ? Ko : Vo;
    int bn = blockIdx.x, bm = blockIdx.y;
    const bf16* Abase = xb + (long)bm * 128 * D_;
    const bf16* Bbase = W  + (long)bn * 128 * D_;

    GEMM_MAINLOOP();

    int mlo = bm*128 + wm*64;
    int nlo = bn*128 + wn*64;
    #pragma unroll
    for (int mt = 0; mt < 4; ++mt) {
        #pragma unroll
        for (int nt = 0; nt < 4; ++nt) {
            int n = nlo + nt*16 + (lane & 15);
            int h = n >> 7, hd = n & 127;
            #pragma unroll
            for (int r = 0; r < 4; ++r) {
                int m = mlo + mt*16 + (lane >> 4)*4 + r;     // C/D: row=(l>>4)*4+r, col=l&15
                int b = m >> 11, t = m & 2047;
                out[(((long)(b*H_ + h))*T_ + t)*HD_ + hd] = __float2bfloat16(acc[mt][nt][r]);
            }
        }
    }
}

// ---------- causal flash attention, fixed-max softmax, K/V register prefetch ----------
// grid: 512 1-D blocks (heavy-first), block 256
__global__ __launch_bounds__(256) void attn(
    const bf16* __restrict__ Qm, const bf16* __restrict__ Km, const bf16* __restrict__ Vm,
    bf16* __restrict__ Om)   // Om in [B,T,D]
{
    __shared__ bf16 Ks[64*136];     // K tile [pos][d], +8 pad
    __shared__ bf16 Vt[128*72];     // V tile transposed Vt[d][pos], +8 pad
    __shared__ bf16 Ps[128*72];     // P round-trip (per-wave private rows)
    int bm = 15 - (blockIdx.x >> 5);        // heavy blocks dispatch first
    int bh = blockIdx.x & 31;
    int tid = threadIdx.x, lane = tid & 63, w = tid >> 6;
    const float c1 = 0.12754012780914427f;  // (1/sqrt(128)) * log2(e)
    const float c2 = 23.083120654223414f;   // 16 * log2(e)  (fixed max M=16)
    const bf16* Qb = Qm + (long)bh*T_*HD_;
    const bf16* Kb = Km + (long)bh*T_*HD_;
    const bf16* Vb = Vm + (long)bh*T_*HD_;
    int m0 = bm*128 + w*32;                 // this wave's 32 Q rows

    // Q fragments in regs for whole block
    bf16x8 qf[2][4];
    #pragma unroll
    for (int mt = 0; mt < 2; ++mt)
        #pragma unroll
        for (int ks = 0; ks < 4; ++ks)
            qf[mt][ks] = *(const bf16x8*)(Qb + (long)(m0 + mt*16 + (lane & 15))*HD_ + ks*32 + (lane >> 4)*8);

    // ones B-fragment: B[k][0]=1 -> row-sum of P rides the MFMA pipe
    bf16x8 onesB;
    {
        short v1 = ((lane & 15) == 0) ? (short)0x3F80 : (short)0;
        #pragma unroll
        for (int jj = 0; jj < 8; ++jj) onesB[jj] = v1;
    }

    f32x4 oacc[2][8];
    f32x4 lacc[2];
    #pragma unroll
    for (int mt = 0; mt < 2; ++mt) {
        lacc[mt] = f32x4{0.f,0.f,0.f,0.f};
        #pragma unroll
        for (int dt = 0; dt < 8; ++dt) oacc[mt][dt] = f32x4{0.f,0.f,0.f,0.f};
    }

    int krow = (tid >> 4);          // + i*16
    int kcg  = tid & 15;
    int njt = 2*bm + 2;             // causal: K/V tiles 0..2bm+1

    // prefetch tile 0 into regs
    bf16x8 kreg[4], vreg[4];
    #pragma unroll
    for (int i = 0; i < 4; ++i) {
        kreg[i] = *(const bf16x8*)(Kb + (long)(i*16 + krow)*HD_ + kcg*8);
        vreg[i] = *(const bf16x8*)(Vb + (long)lane*HD_ + (w + i*4)*8);
    }

    for (int j = 0; j < njt; ++j) {
        int j0 = j*64;
        __syncthreads();                         // all waves done reading prev Ks/Vt
        #pragma unroll
        for (int i = 0; i < 4; ++i)              // K regs -> LDS (vector)
            *(bf16x8*)&Ks[(i*16 + krow)*136 + kcg*8] = kreg[i];
        #pragma unroll
        for (int i = 0; i < 4; ++i) {            // V regs -> LDS transposed (scatter)
            int dg = w + i*4;
            union { bf16 h[8]; bf16x8 v; } u;
            u.v = vreg[i];
            #pragma unroll
            for (int jj = 0; jj < 8; ++jj)
                Vt[(dg*8 + jj)*72 + lane] = u.h[jj];
        }
        __syncthreads();

        // issue prefetch for tile j+1 (overlaps with compute below)
        if (j + 1 < njt) {
            int jn0 = j0 + 64;
            #pragma unroll
            for (int i = 0; i < 4; ++i) {
                kreg[i] = *(const bf16x8*)(Kb + (long)(jn0 + i*16 + krow)*HD_ + kcg*8);
                vreg[i] = *(const bf16x8*)(Vb + (long)(jn0 + lane)*HD_ + (w + i*4)*8);
            }
        }

        bool anyv  = (j0 <= m0 + 31);            // wave-uniform: any visible column?
        if (anyv) {
            bool bmask = (j0 + 63 > m0);         // wave-uniform: boundary tile?
            // S = Q K^T  (32 rows x 64 cols per wave)
            f32x4 s[2][4];
            #pragma unroll
            for (int mt = 0; mt < 2; ++mt)
                #pragma unroll
                for (int nt = 0; nt < 4; ++nt) s[mt][nt] = f32x4{0.f,0.f,0.f,0.f};
            #pragma unroll
            for (int ks = 0; ks < 4; ++ks) {
                bf16x8 kf[4];
                #pragma unroll
                for (int nt = 0; nt < 4; ++nt)
                    kf[nt] = *(const bf16x8*)&Ks[(nt*16 + (lane & 15))*136 + ks*32 + (lane >> 4)*8];
                #pragma unroll
                for (int mt = 0; mt < 2; ++mt)
                    #pragma unroll
                    for (int nt = 0; nt < 4; ++nt)
                        s[mt][nt] = mfma16(qf[mt][ks], kf[nt], s[mt][nt]);
            }
            // fixed-max softmax: p = exp2(s*c1 - c2); no reductions, no rescale
            #pragma unroll
            for (int mt = 0; mt < 2; ++mt) {
                #pragma unroll
                for (int nt = 0; nt < 4; ++nt) {
                    int n = j0 + nt*16 + (lane & 15);
                    #pragma unroll
                    for (int r = 0; r < 4; ++r) {
                        float x = s[mt][nt][r] * c1 - c2;
                        if (bmask) {
                            int mg = m0 + mt*16 + (lane >> 4)*4 + r;
                            x = (n <= mg) ? x : -1e30f;
                        }
                        float p = exp2f(x);
                        int prow = w*32 + mt*16 + (lane >> 4)*4 + r;
                        Ps[prow*72 + nt*16 + (lane & 15)] = __float2bfloat16(p);
                    }
                }
            }
            // O += P V ; l += P 1   (P via LDS C->A layout; V via Vt: ds_read_b128)
            #pragma unroll
            for (int kn = 0; kn < 2; ++kn) {
                bf16x8 pf[2], vf[8];
                #pragma unroll
                for (int mt = 0; mt < 2; ++mt)
                    pf[mt] = *(const bf16x8*)&Ps[(w*32 + mt*16 + (lane & 15))*72 + kn*32 + (lane >> 4)*8];
                #pragma unroll
                for (int dt = 0; dt < 8; ++dt)
                    vf[dt] = *(const bf16x8*)&Vt[(dt*16 + (lane & 15))*72 + kn*32 + (lane >> 4)*8];
                #pragma unroll
                for (int mt = 0; mt < 2; ++mt)
                    lacc[mt] = mfma16(pf[mt], onesB, lacc[mt]);
                #pragma unroll
                for (int mt = 0; mt < 2; ++mt)
                    #pragma unroll
                    for (int dt = 0; dt < 8; ++dt)
                        oacc[mt][dt] = mfma16(pf[mt], vf[dt], oacc[mt][dt]);
            }
        }
    }
    // epilogue: broadcast row sums (col 0 lives at lane&15==0), normalize, store
    int b = bh >> 4, h = bh & 15;
    #pragma unroll
    for (int mt = 0; mt < 2; ++mt) {
        #pragma unroll
        for (int r = 0; r < 4; ++r) {
            float l = __shfl(lacc[mt][r], lane & 48, 64);
            float inv = 1.f / l;
            int t = m0 + mt*16 + (lane >> 4)*4 + r;
            #pragma unroll
            for (int dt = 0; dt < 8; ++dt) {
                int d = dt*16 + (lane & 15);
                Om[((long)(b*T_ + t))*D_ + h*HD_ + d] = __float2bfloat16(oacc[mt][dt][r] * inv);
            }
        }
    }
}

// ---------- output projection: fp32 out = O @ Wo^T + bo ----------
__global__ __launch_bounds__(256) void gemm_out(
    const bf16* __restrict__ Ab, const bf16* __restrict__ Wob,
    const float* __restrict__ bo, float* __restrict__ out)
{
    __shared__ bf16 As[3][128*32];
    __shared__ bf16 Bs[3][128*32];
    int bn = blockIdx.x, bm = blockIdx.y;
    const bf16* Abase = Ab  + (long)bm * 128 * D_;
    const bf16* Bbase = Wob + (long)bn * 128 * D_;

    GEMM_MAINLOOP();

    int mlo = bm*128 + wm*64;
    int nlo = bn*128 + wn*64;
    #pragma unroll
    for (int mt = 0; mt < 4; ++mt) {
        #pragma unroll
        for (int nt = 0; nt < 4; ++nt) {
            int n = nlo + nt*16 + (lane & 15);
            float bias = bo[n];
            #pragma unroll
            for (int r = 0; r < 4; ++r) {
                int m = mlo + mt*16 + (lane >> 4)*4 + r;
                out[(long)m*D_ + n] = acc[mt][nt][r] + bias;
            }
        }
    }
}

extern "C" void kernel_launch(void* const* d_in, const int* in_sizes, int n_in,
                              void* d_out, int out_size, void* d_ws, size_t ws_size,
                              hipStream_t stream) {
    const float* x  = (const float*)d_in[0];
    const float* Wq = (const float*)d_in[1];
    const float* Wk = (const float*)d_in[2];
    const float* Wv = (const float*)d_in[3];
    const float* Wo = (const float*)d_in[4];
    const float* bo = (const float*)d_in[5];
    float* out = (float*)d_out;

    bf16* ws  = (bf16*)d_ws;
    bf16* xb  = ws;                    // 8388608 elems [B*T, D], later reused as attn output O
    bf16* wqb = ws + 8388608L;         // 4194304 each
    bf16* wkb = ws + 12582912L;
    bf16* wvb = ws + 16777216L;
    bf16* wob = ws + 20971520L;
    bf16* Qb  = ws + 25165824L;        // [B,H,T,HD] 8388608 each
    bf16* Kb  = ws + 33554432L;
    bf16* Vb  = ws + 41943040L;
    bf16* Ob  = xb;                    // reuse (xb dead after gemm_qkv)

    cast6<<<dim3(2048, 6), 256, 0, stream>>>(x, x + 4194304L, Wq, Wk, Wv, Wo, ws);
    gemm_qkv<<<dim3(16, 32, 3), 256, 0, stream>>>(xb, wqb, wkb, wvb, Qb, Kb, Vb);
    attn<<<512, 256, 0, stream>>>(Qb, Kb, Vb, Ob);
    gemm_out<<<dim3(16, 32), 256, 0, stream>>>(Ob, wob, bo, out);
}